// Round 5
// baseline (199.710 us; speedup 1.0000x reference)
//
#include <hip/hip_runtime.h>
#include <cstdint>
#include <cstddef>

// Problem constants
#define NHEADS 16
#define HDIM   64
#define EMBED  1024
#define BATCH  2
#define SEQ    2048
#define BH     (BATCH*NHEADS)        // 32
#define MTOK   (BATCH*SEQ)           // 4096
#define NQKV   (3*NHEADS*HDIM)       // 3072

typedef _Float16 f16;
typedef __attribute__((ext_vector_type(4))) _Float16 f16x4;
typedef __attribute__((ext_vector_type(8))) _Float16 f16x8;
typedef __attribute__((ext_vector_type(4))) float f32x4;
typedef __attribute__((ext_vector_type(16))) float f32x16;

// pack two f32 -> one u32 of 2 f16 (RTZ)
__device__ __forceinline__ unsigned pkf16(float a, float b) {
    return __builtin_bit_cast(unsigned, __builtin_amdgcn_cvt_pkrtz(a, b));
}
// cross-32-lane max/add. shfl_xor-based: HW-proven in round 2. The
// permlane32_swap asm variants (rounds 3/4) produced identical wrong results
// regardless of register-allocation fixes — do not reintroduce without an
// isolated A/B probe.
__device__ __forceinline__ float cross32_max(float x) {
    return fmaxf(x, __shfl_xor(x, 32, 64));
}
__device__ __forceinline__ float cross32_add(float x) {
    return x + __shfl_xor(x, 32, 64);
}

// ---------------------------------------------------------------------------
// Transpose + fp32->f16 convert:  out[n][k] = (f16) in[k][n]
// ---------------------------------------------------------------------------
__global__ __launch_bounds__(256) void transpose_cvt_kernel(
    const float* __restrict__ in, f16* __restrict__ out, int K, int N)
{
    __shared__ float tile[32][33];
    const int n0 = blockIdx.x * 32;
    const int k0 = blockIdx.y * 32;
    const int tx = threadIdx.x & 31;
    const int ty = threadIdx.x >> 5;
#pragma unroll
    for (int j = 0; j < 4; ++j) {
        int k = ty + j * 8;
        tile[k][tx] = in[(size_t)(k0 + k) * N + n0 + tx];
    }
    __syncthreads();
#pragma unroll
    for (int j = 0; j < 4; ++j) {
        int n = ty + j * 8;
        out[(size_t)(n0 + n) * K + k0 + tx] = (f16)tile[tx][n];
    }
}

// ---------------------------------------------------------------------------
// GEMM1: QKV = X @ Wqkv + b  (M=4096, N=3072, K=1024)
// ---------------------------------------------------------------------------
__global__ __launch_bounds__(256, 2) void gemm_qkv_kernel(
    const float* __restrict__ X, const f16* __restrict__ WT,
    const float* __restrict__ bqkv,
    f16* __restrict__ Qb, f16* __restrict__ Kb, f16* __restrict__ Vt)
{
    __shared__ f16 As[128 * 32];
    __shared__ f16 Bs[128 * 32];
    const int tid = threadIdx.x;
    const int lane = tid & 63;
    const int wid = tid >> 6;
    const int wr = wid >> 1, wc = wid & 1;
    const int lhi = lane >> 4, llo = lane & 15;
    const int row0 = blockIdx.x * 128;
    const int col0 = blockIdx.y * 128;

    f32x4 acc[4][4] = {};

    for (int k0 = 0; k0 < EMBED; k0 += 32) {
        __syncthreads();
#pragma unroll
        for (int i = 0; i < 4; ++i) {
            int li = i * 256 + tid;
            int ar = li >> 3;
            int ac = (li & 7) * 4;
            float4 v = *reinterpret_cast<const float4*>(
                &X[(size_t)(row0 + ar) * EMBED + k0 + ac]);
            int byte = (ac * 2) ^ ((ar & 3) << 4);
            f16x4 h;
            h[0] = (f16)v.x; h[1] = (f16)v.y; h[2] = (f16)v.z; h[3] = (f16)v.w;
            *reinterpret_cast<f16x4*>((char*)As + ar * 64 + byte) = h;
        }
#pragma unroll
        for (int i = 0; i < 2; ++i) {
            int li = i * 256 + tid;
            int br = li >> 2;
            int bc = (li & 3) * 8;
            f16x8 v = *reinterpret_cast<const f16x8*>(
                &WT[(size_t)(col0 + br) * EMBED + k0 + bc]);
            int byte = (bc * 2) ^ ((br & 3) << 4);
            *reinterpret_cast<f16x8*>((char*)Bs + br * 64 + byte) = v;
        }
        __syncthreads();
        f16x8 af[4], bf[4];
#pragma unroll
        for (int m = 0; m < 4; ++m) {
            int ar = wr * 64 + m * 16 + llo;
            int byte = (lhi * 16) ^ ((ar & 3) << 4);
            af[m] = *reinterpret_cast<const f16x8*>((const char*)As + ar * 64 + byte);
        }
#pragma unroll
        for (int n = 0; n < 4; ++n) {
            int br = wc * 64 + n * 16 + llo;
            int byte = (lhi * 16) ^ ((br & 3) << 4);
            bf[n] = *reinterpret_cast<const f16x8*>((const char*)Bs + br * 64 + byte);
        }
#pragma unroll
        for (int m = 0; m < 4; ++m)
#pragma unroll
            for (int n = 0; n < 4; ++n)
                acc[m][n] = __builtin_amdgcn_mfma_f32_16x16x32_f16(
                    af[m], bf[n], acc[m][n], 0, 0, 0);
    }

#pragma unroll
    for (int m = 0; m < 4; ++m) {
#pragma unroll
        for (int n = 0; n < 4; ++n) {
#pragma unroll
            for (int r = 0; r < 4; ++r) {
                int mg = row0 + wr * 64 + m * 16 + lhi * 4 + r;
                int ng = col0 + wc * 64 + n * 16 + llo;
                float v = acc[m][n][r] + bqkv[ng];
                int t = ng >> 10;
                int h = (ng >> 6) & 15;
                int d = ng & 63;
                int b = mg >> 11;
                int s = mg & (SEQ - 1);
                int bh = b * NHEADS + h;
                if (t == 0)
                    Qb[((size_t)bh * SEQ + s) * HDIM + d] = (f16)(v * 0.18033688011f);
                else if (t == 1)
                    Kb[((size_t)bh * SEQ + s) * HDIM + d] = (f16)v;
                else
                    Vt[((size_t)bh * HDIM + d) * SEQ + s] = (f16)v;
            }
        }
    }
}

// ---------------------------------------------------------------------------
// Flash attention, swapped-operand in-register softmax + register pipelining.
// Grid (BH, SEQ/128); 4 waves/block, each wave owns 32 q rows, KVBLK=64.
// K double-buffered in regs (prefetch next iter); V loaded at iteration top
// (first use ~600cyc later in PV). Tree reductions for row max/sum;
// shfl_xor for cross-half combine. setprio(1) around MFMA clusters.
// ---------------------------------------------------------------------------
#define LOADK(KF, KB) do {                                                     \
    const f16* kbase_ = Kp + (size_t)(KB) * HDIM;                              \
    _Pragma("unroll")                                                          \
    for (int j_ = 0; j_ < 2; ++j_)                                             \
        _Pragma("unroll")                                                      \
        for (int ds_ = 0; ds_ < 4; ++ds_)                                      \
            KF[j_*4+ds_] = *reinterpret_cast<const f16x8*>(                    \
                kbase_ + (size_t)(j_*32 + q) * HDIM + ds_*16 + hi*8);          \
} while (0)

#define LOADV(VF, KB) do {                                                     \
    _Pragma("unroll")                                                          \
    for (int dt_ = 0; dt_ < 2; ++dt_)                                          \
        _Pragma("unroll")                                                      \
        for (int f_ = 0; f_ < 4; ++f_)                                         \
            VF[dt_*4+f_] = *reinterpret_cast<const f16x8*>(                    \
                Vp + (size_t)(dt_*32 + q) * SEQ + (KB) + f_*16 + hi*8);        \
} while (0)

#define STEP(KF, VF) do {                                                      \
    f32x16 st0 = {}, st1 = {};                                                 \
    __builtin_amdgcn_s_setprio(1);                                             \
    _Pragma("unroll")                                                          \
    for (int ds_ = 0; ds_ < 4; ++ds_) {                                        \
        st0 = __builtin_amdgcn_mfma_f32_32x32x16_f16(KF[ds_],   qf[ds_], st0, 0, 0, 0); \
        st1 = __builtin_amdgcn_mfma_f32_32x32x16_f16(KF[4+ds_], qf[ds_], st1, 0, 0, 0); \
    }                                                                          \
    __builtin_amdgcn_s_setprio(0);                                             \
    float red[16];                                                             \
    _Pragma("unroll")                                                          \
    for (int r_ = 0; r_ < 16; ++r_) red[r_] = fmaxf(st0[r_], st1[r_]);         \
    _Pragma("unroll")                                                          \
    for (int w_ = 8; w_ >= 1; w_ >>= 1)                                        \
        _Pragma("unroll")                                                      \
        for (int r_ = 0; r_ < w_; ++r_) red[r_] = fmaxf(red[r_], red[r_+w_]);  \
    float pm = cross32_max(red[0]);                                            \
    if (!__all(pm - m <= 8.0f)) {                                              \
        float mn = fmaxf(m, pm);                                               \
        float sc = __builtin_amdgcn_exp2f(m - mn);                             \
        m = mn; l *= sc;                                                       \
        _Pragma("unroll")                                                      \
        for (int r_ = 0; r_ < 16; ++r_) { o[0][r_] *= sc; o[1][r_] *= sc; }    \
    }                                                                          \
    _Pragma("unroll")                                                          \
    for (int r_ = 0; r_ < 16; ++r_) {                                          \
        st0[r_] = __builtin_amdgcn_exp2f(st0[r_] - m);                         \
        st1[r_] = __builtin_amdgcn_exp2f(st1[r_] - m);                         \
    }                                                                          \
    _Pragma("unroll")                                                          \
    for (int r_ = 0; r_ < 16; ++r_) red[r_] = st0[r_] + st1[r_];               \
    _Pragma("unroll")                                                          \
    for (int w_ = 8; w_ >= 1; w_ >>= 1)                                        \
        _Pragma("unroll")                                                      \
        for (int r_ = 0; r_ < w_; ++r_) red[r_] += red[r_+w_];                 \
    l += red[0];                                                               \
    f16x8 pf[4];                                                               \
    {                                                                          \
        unsigned a0 = pkf16(st0[0],  st0[1]),  a1 = pkf16(st0[2],  st0[3]);    \
        unsigned b0 = pkf16(st0[4],  st0[5]),  b1 = pkf16(st0[6],  st0[7]);    \
        unsigned c0 = pkf16(st0[8],  st0[9]),  c1 = pkf16(st0[10], st0[11]);   \
        unsigned d0 = pkf16(st0[12], st0[13]), d1 = pkf16(st0[14], st0[15]);   \
        asm("v_permlane32_swap_b32 %0, %1" : "+v"(a0), "+v"(b0));              \
        asm("v_permlane32_swap_b32 %0, %1" : "+v"(a1), "+v"(b1));              \
        asm("v_permlane32_swap_b32 %0, %1" : "+v"(c0), "+v"(d0));              \
        asm("v_permlane32_swap_b32 %0, %1" : "+v"(c1), "+v"(d1));              \
        uint4 w0; w0.x = a0; w0.y = a1; w0.z = b0; w0.w = b1;                  \
        uint4 w1; w1.x = c0; w1.y = c1; w1.z = d0; w1.w = d1;                  \
        pf[0] = __builtin_bit_cast(f16x8, w0);                                 \
        pf[1] = __builtin_bit_cast(f16x8, w1);                                 \
    }                                                                          \
    {                                                                          \
        unsigned a0 = pkf16(st1[0],  st1[1]),  a1 = pkf16(st1[2],  st1[3]);    \
        unsigned b0 = pkf16(st1[4],  st1[5]),  b1 = pkf16(st1[6],  st1[7]);    \
        unsigned c0 = pkf16(st1[8],  st1[9]),  c1 = pkf16(st1[10], st1[11]);   \
        unsigned d0 = pkf16(st1[12], st1[13]), d1 = pkf16(st1[14], st1[15]);   \
        asm("v_permlane32_swap_b32 %0, %1" : "+v"(a0), "+v"(b0));              \
        asm("v_permlane32_swap_b32 %0, %1" : "+v"(a1), "+v"(b1));              \
        asm("v_permlane32_swap_b32 %0, %1" : "+v"(c0), "+v"(d0));              \
        asm("v_permlane32_swap_b32 %0, %1" : "+v"(c1), "+v"(d1));              \
        uint4 w0; w0.x = a0; w0.y = a1; w0.z = b0; w0.w = b1;                  \
        uint4 w1; w1.x = c0; w1.y = c1; w1.z = d0; w1.w = d1;                  \
        pf[2] = __builtin_bit_cast(f16x8, w0);                                 \
        pf[3] = __builtin_bit_cast(f16x8, w1);                                 \
    }                                                                          \
    __builtin_amdgcn_s_setprio(1);                                             \
    _Pragma("unroll")                                                          \
    for (int dt_ = 0; dt_ < 2; ++dt_)                                          \
        _Pragma("unroll")                                                      \
        for (int f_ = 0; f_ < 4; ++f_)                                         \
            o[dt_] = __builtin_amdgcn_mfma_f32_32x32x16_f16(                   \
                VF[dt_*4+f_], pf[f_], o[dt_], 0, 0, 0);                        \
    __builtin_amdgcn_s_setprio(0);                                             \
} while (0)

__global__ __launch_bounds__(256, 2) void attn_kernel(
    const f16* __restrict__ Qb, const f16* __restrict__ Kb,
    const f16* __restrict__ Vt, f16* __restrict__ ctx)
{
    __shared__ f16 Ol[4][32 * 64];   // 16KB: per-warp output transpose patch
    const int tid = threadIdx.x;
    const int lane = tid & 63;
    const int wid = tid >> 6;
    const int q = lane & 31;
    const int hi = lane >> 5;
    const int bh = blockIdx.x;
    const int q0 = blockIdx.y * 128 + wid * 32;
    const f16* Qp = Qb + (size_t)bh * SEQ * HDIM;
    const f16* Kp = Kb + (size_t)bh * SEQ * HDIM;
    const f16* Vp = Vt + (size_t)bh * HDIM * SEQ;

    f16x8 qf[4];
#pragma unroll
    for (int ds = 0; ds < 4; ++ds)
        qf[ds] = *reinterpret_cast<const f16x8*>(
            Qp + (size_t)(q0 + q) * HDIM + ds * 16 + hi * 8);

    f32x16 o[2] = {};
    float m = -1e30f, l = 0.f;

    f16x8 ka[8], kn[8], va[8];
    LOADK(ka, 0);
    for (int kb = 0; kb < SEQ; kb += 128) {
        LOADV(va, kb);
        LOADK(kn, kb + 64);
        STEP(ka, va);
        LOADV(va, kb + 64);
        LOADK(ka, (kb + 128) & (SEQ - 1));
        STEP(kn, va);
    }

    // ---- epilogue: normalize, transpose via swizzled LDS, coalesced store
    float lt = cross32_add(l);
    float inv = __builtin_amdgcn_rcpf(lt);
    char* base = (char*)&Ol[wid][0];
#pragma unroll
    for (int dt = 0; dt < 2; ++dt)
#pragma unroll
        for (int rp = 0; rp < 8; ++rp) {
            int r = rp * 2;
            int d = dt * 32 + (r & 3) + 8 * (r >> 2) + 4 * hi;
            unsigned w = pkf16(o[dt][r] * inv, o[dt][r + 1] * inv);
            int byte = (q * 128 + d * 2) ^ ((q & 7) << 4);
            *reinterpret_cast<unsigned*>(base + byte) = w;
        }
    __syncthreads();
    {
        int row = lane >> 1, half = lane & 1;
        const char* rb = base + row * 128;
        int b = bh >> 4, h = bh & 15;
        f16* orow = ctx + (size_t)(b * SEQ + q0 + row) * EMBED + h * HDIM;
#pragma unroll
        for (int i = 0; i < 4; ++i) {
            int c = half * 64 + i * 16;
            int4 v = *reinterpret_cast<const int4*>(rb + (c ^ ((row & 7) << 4)));
            *reinterpret_cast<int4*>((char*)orow + c) = v;
        }
    }
}

// ---------------------------------------------------------------------------
// GEMM2: out = ctx @ Wo + bo  (M=4096, N=1024, K=1024), fp32 output.
// ---------------------------------------------------------------------------
__global__ __launch_bounds__(256, 2) void gemm_out_kernel(
    const f16* __restrict__ A, const f16* __restrict__ WT,
    const float* __restrict__ bo, float* __restrict__ out)
{
    __shared__ f16 As[128 * 32];
    __shared__ f16 Bs[128 * 32];
    const int tid = threadIdx.x;
    const int lane = tid & 63;
    const int wid = tid >> 6;
    const int wr = wid >> 1, wc = wid & 1;
    const int lhi = lane >> 4, llo = lane & 15;
    const int row0 = blockIdx.x * 128;
    const int col0 = blockIdx.y * 128;

    f32x4 acc[4][4] = {};

    for (int k0 = 0; k0 < EMBED; k0 += 32) {
        __syncthreads();
#pragma unroll
        for (int i = 0; i < 2; ++i) {
            int li = i * 256 + tid;
            int ar = li >> 2;
            int ac = (li & 3) * 8;
            f16x8 v = *reinterpret_cast<const f16x8*>(
                &A[(size_t)(row0 + ar) * EMBED + k0 + ac]);
            int byte = (ac * 2) ^ ((ar & 3) << 4);
            *reinterpret_cast<f16x8*>((char*)As + ar * 64 + byte) = v;
        }
#pragma unroll
        for (int i = 0; i < 2; ++i) {
            int li = i * 256 + tid;
            int br = li >> 2;
            int bc = (li & 3) * 8;
            f16x8 v = *reinterpret_cast<const f16x8*>(
                &WT[(size_t)(col0 + br) * EMBED + k0 + bc]);
            int byte = (bc * 2) ^ ((br & 3) << 4);
            *reinterpret_cast<f16x8*>((char*)Bs + br * 64 + byte) = v;
        }
        __syncthreads();
        f16x8 af[4], bf[4];
#pragma unroll
        for (int m = 0; m < 4; ++m) {
            int ar = wr * 64 + m * 16 + llo;
            int byte = (lhi * 16) ^ ((ar & 3) << 4);
            af[m] = *reinterpret_cast<const f16x8*>((const char*)As + ar * 64 + byte);
        }
#pragma unroll
        for (int n = 0; n < 4; ++n) {
            int br = wc * 64 + n * 16 + llo;
            int byte = (lhi * 16) ^ ((br & 3) << 4);
            bf[n] = *reinterpret_cast<const f16x8*>((const char*)Bs + br * 64 + byte);
        }
#pragma unroll
        for (int m = 0; m < 4; ++m)
#pragma unroll
            for (int n = 0; n < 4; ++n)
                acc[m][n] = __builtin_amdgcn_mfma_f32_16x16x32_f16(
                    af[m], bf[n], acc[m][n], 0, 0, 0);
    }

#pragma unroll
    for (int m = 0; m < 4; ++m)
#pragma unroll
        for (int n = 0; n < 4; ++n)
#pragma unroll
            for (int r = 0; r < 4; ++r) {
                int mg = row0 + wr * 64 + m * 16 + lhi * 4 + r;
                int ng = col0 + wc * 64 + n * 16 + llo;
                out[(size_t)mg * EMBED + ng] = acc[m][n][r] + bo[ng];
            }
}

// ---------------------------------------------------------------------------
extern "C" void kernel_launch(void* const* d_in, const int* in_sizes, int n_in,
                              void* d_out, int out_size, void* d_ws, size_t ws_size,
                              hipStream_t stream)
{
    const float* x     = (const float*)d_in[0];
    const float* w_qkv = (const float*)d_in[1];
    const float* b_qkv = (const float*)d_in[2];
    const float* w_o   = (const float*)d_in[3];
    const float* b_o   = (const float*)d_in[4];
    float* out = (float*)d_out;

    char* ws = (char*)d_ws;
    f16* wqkvT = (f16*)ws; ws += (size_t)NQKV * EMBED * 2;
    f16* woT   = (f16*)ws; ws += (size_t)EMBED * EMBED * 2;
    f16* Qb    = (f16*)ws; ws += (size_t)BH * SEQ * HDIM * 2;
    f16* Kb    = (f16*)ws; ws += (size_t)BH * SEQ * HDIM * 2;
    f16* Vt    = (f16*)ws; ws += (size_t)BH * SEQ * HDIM * 2;
    f16* ctx   = (f16*)ws; ws += (size_t)MTOK * EMBED * 2;

    hipLaunchKernelGGL(transpose_cvt_kernel, dim3(NQKV / 32, EMBED / 32), dim3(256),
                       0, stream, w_qkv, wqkvT, EMBED, NQKV);
    hipLaunchKernelGGL(transpose_cvt_kernel, dim3(EMBED / 32, EMBED / 32), dim3(256),
                       0, stream, w_o, woT, EMBED, EMBED);
    hipLaunchKernelGGL(gemm_qkv_kernel, dim3(MTOK / 128, NQKV / 128), dim3(256),
                       0, stream, x, wqkvT, b_qkv, Qb, Kb, Vt);
    hipLaunchKernelGGL(attn_kernel, dim3(BH, SEQ / 128), dim3(256),
                       0, stream, Qb, Kb, Vt, ctx);
    hipLaunchKernelGGL(gemm_out_kernel, dim3(MTOK / 128, EMBED / 128), dim3(256),
                       0, stream, ctx, woT, b_o, out);
}

// Round 6
// 134.210 us; speedup vs baseline: 1.4880x; 1.4880x over previous
//
#include <hip/hip_runtime.h>
#include <cstdint>
#include <cstddef>

// Problem constants
#define NHEADS 16
#define HDIM   64
#define EMBED  1024
#define BATCH  2
#define SEQ    2048
#define BH     (BATCH*NHEADS)        // 32
#define MTOK   (BATCH*SEQ)           // 4096
#define NQKV   (3*NHEADS*HDIM)       // 3072

typedef _Float16 f16;
typedef __attribute__((ext_vector_type(4))) _Float16 f16x4;
typedef __attribute__((ext_vector_type(8))) _Float16 f16x8;
typedef __attribute__((ext_vector_type(4))) float f32x4;
typedef __attribute__((ext_vector_type(16))) float f32x16;

// pack two f32 -> one u32 of 2 f16 (RTZ)
__device__ __forceinline__ unsigned pkf16(float a, float b) {
    return __builtin_bit_cast(unsigned, __builtin_amdgcn_cvt_pkrtz(a, b));
}
// cross-32-lane max/add. shfl_xor-based: HW-proven in round 2/5.
__device__ __forceinline__ float cross32_max(float x) {
    return fmaxf(x, __shfl_xor(x, 32, 64));
}
__device__ __forceinline__ float cross32_add(float x) {
    return x + __shfl_xor(x, 32, 64);
}

// ---------------------------------------------------------------------------
// Transpose + fp32->f16 convert:  out[n][k] = (f16) in[k][n]
// ---------------------------------------------------------------------------
__global__ __launch_bounds__(256) void transpose_cvt_kernel(
    const float* __restrict__ in, f16* __restrict__ out, int K, int N)
{
    __shared__ float tile[32][33];
    const int n0 = blockIdx.x * 32;
    const int k0 = blockIdx.y * 32;
    const int tx = threadIdx.x & 31;
    const int ty = threadIdx.x >> 5;
#pragma unroll
    for (int j = 0; j < 4; ++j) {
        int k = ty + j * 8;
        tile[k][tx] = in[(size_t)(k0 + k) * N + n0 + tx];
    }
    __syncthreads();
#pragma unroll
    for (int j = 0; j < 4; ++j) {
        int n = ty + j * 8;
        out[(size_t)(n0 + n) * K + k0 + tx] = (f16)tile[tx][n];
    }
}

// ---------------------------------------------------------------------------
// GEMM1: QKV = X @ Wqkv + b  (M=4096, N=3072, K=1024)
// Epilogue: Q row-major (scaled 0.125*log2e), K and V in MFMA-FRAGMENT order
// so attention loads are base + lane*16B (fully coalesced):
//   Kf[bh][s/32][ds=d/16][lane = (d>>3&1)*32 + s%32][e = d%8]
//   Vf[bh][s/64][(d/32)*4 + (s%64)/16][lane = (s>>3&1)*32 + d%32][e = s%8]
// ---------------------------------------------------------------------------
__global__ __launch_bounds__(256, 2) void gemm_qkv_kernel(
    const float* __restrict__ X, const f16* __restrict__ WT,
    const float* __restrict__ bqkv,
    f16* __restrict__ Qb, f16* __restrict__ Kb, f16* __restrict__ Vt)
{
    __shared__ f16 As[128 * 32];
    __shared__ f16 Bs[128 * 32];
    const int tid = threadIdx.x;
    const int lane = tid & 63;
    const int wid = tid >> 6;
    const int wr = wid >> 1, wc = wid & 1;
    const int lhi = lane >> 4, llo = lane & 15;
    const int row0 = blockIdx.x * 128;
    const int col0 = blockIdx.y * 128;

    f32x4 acc[4][4] = {};

    for (int k0 = 0; k0 < EMBED; k0 += 32) {
        __syncthreads();
#pragma unroll
        for (int i = 0; i < 4; ++i) {
            int li = i * 256 + tid;
            int ar = li >> 3;
            int ac = (li & 7) * 4;
            float4 v = *reinterpret_cast<const float4*>(
                &X[(size_t)(row0 + ar) * EMBED + k0 + ac]);
            int byte = (ac * 2) ^ ((ar & 3) << 4);
            f16x4 h;
            h[0] = (f16)v.x; h[1] = (f16)v.y; h[2] = (f16)v.z; h[3] = (f16)v.w;
            *reinterpret_cast<f16x4*>((char*)As + ar * 64 + byte) = h;
        }
#pragma unroll
        for (int i = 0; i < 2; ++i) {
            int li = i * 256 + tid;
            int br = li >> 2;
            int bc = (li & 3) * 8;
            f16x8 v = *reinterpret_cast<const f16x8*>(
                &WT[(size_t)(col0 + br) * EMBED + k0 + bc]);
            int byte = (bc * 2) ^ ((br & 3) << 4);
            *reinterpret_cast<f16x8*>((char*)Bs + br * 64 + byte) = v;
        }
        __syncthreads();
        f16x8 af[4], bf[4];
#pragma unroll
        for (int m = 0; m < 4; ++m) {
            int ar = wr * 64 + m * 16 + llo;
            int byte = (lhi * 16) ^ ((ar & 3) << 4);
            af[m] = *reinterpret_cast<const f16x8*>((const char*)As + ar * 64 + byte);
        }
#pragma unroll
        for (int n = 0; n < 4; ++n) {
            int br = wc * 64 + n * 16 + llo;
            int byte = (lhi * 16) ^ ((br & 3) << 4);
            bf[n] = *reinterpret_cast<const f16x8*>((const char*)Bs + br * 64 + byte);
        }
#pragma unroll
        for (int m = 0; m < 4; ++m)
#pragma unroll
            for (int n = 0; n < 4; ++n)
                acc[m][n] = __builtin_amdgcn_mfma_f32_16x16x32_f16(
                    af[m], bf[n], acc[m][n], 0, 0, 0);
    }

#pragma unroll
    for (int m = 0; m < 4; ++m) {
#pragma unroll
        for (int n = 0; n < 4; ++n) {
#pragma unroll
            for (int r = 0; r < 4; ++r) {
                int mg = row0 + wr * 64 + m * 16 + lhi * 4 + r;
                int ng = col0 + wc * 64 + n * 16 + llo;
                float v = acc[m][n][r] + bqkv[ng];
                int t = ng >> 10;
                int h = (ng >> 6) & 15;
                int d = ng & 63;
                int b = mg >> 11;
                int s = mg & (SEQ - 1);
                int bh = b * NHEADS + h;
                if (t == 0) {
                    Qb[((size_t)bh * SEQ + s) * HDIM + d] = (f16)(v * 0.18033688011f);
                } else if (t == 1) {
                    size_t off = ((size_t)(bh * (SEQ >> 5) + (s >> 5)) * 4 + (d >> 4)) * 512
                               + (size_t)((((d >> 3) & 1) << 5) + (s & 31)) * 8 + (d & 7);
                    Kb[off] = (f16)v;
                } else {
                    size_t off = ((size_t)(bh * (SEQ >> 6) + (s >> 6)) * 8
                                  + (d >> 5) * 4 + ((s >> 4) & 3)) * 512
                               + (size_t)((((s >> 3) & 1) << 5) + (d & 31)) * 8 + (s & 7);
                    Vt[off] = (f16)v;
                }
            }
        }
    }
}

// ---------------------------------------------------------------------------
// Flash attention: swapped-operand in-register softmax, register pipelining,
// K/V in fragment-contiguous layout -> every load is base + lane*16B
// (64 lanes = 1KB contiguous, fully-used 64B lines, perfectly coalesced).
// Grid (BH, SEQ/128); 4 waves/block, 32 q-rows/wave, KVBLK=64.
// ---------------------------------------------------------------------------
#define LOADK(KF, KB) do {                                                     \
    const f16* kbase_ = Kp + ((size_t)((KB) >> 5) * 4) * 512;                  \
    _Pragma("unroll")                                                          \
    for (int j_ = 0; j_ < 2; ++j_)                                             \
        _Pragma("unroll")                                                      \
        for (int ds_ = 0; ds_ < 4; ++ds_)                                      \
            KF[j_*4+ds_] = *reinterpret_cast<const f16x8*>(                    \
                kbase_ + (size_t)(j_*4 + ds_) * 512 + lane * 8);               \
} while (0)

#define LOADV(VF, KB) do {                                                     \
    const f16* vbase_ = Vp + ((size_t)((KB) >> 6) * 8) * 512;                  \
    _Pragma("unroll")                                                          \
    for (int i_ = 0; i_ < 8; ++i_)                                             \
        VF[i_] = *reinterpret_cast<const f16x8*>(                              \
            vbase_ + (size_t)i_ * 512 + lane * 8);                             \
} while (0)

#define STEP(KF, VF) do {                                                      \
    f32x16 st0 = {}, st1 = {};                                                 \
    __builtin_amdgcn_s_setprio(1);                                             \
    _Pragma("unroll")                                                          \
    for (int ds_ = 0; ds_ < 4; ++ds_) {                                        \
        st0 = __builtin_amdgcn_mfma_f32_32x32x16_f16(KF[ds_],   qf[ds_], st0, 0, 0, 0); \
        st1 = __builtin_amdgcn_mfma_f32_32x32x16_f16(KF[4+ds_], qf[ds_], st1, 0, 0, 0); \
    }                                                                          \
    __builtin_amdgcn_s_setprio(0);                                             \
    float red[16];                                                             \
    _Pragma("unroll")                                                          \
    for (int r_ = 0; r_ < 16; ++r_) red[r_] = fmaxf(st0[r_], st1[r_]);         \
    _Pragma("unroll")                                                          \
    for (int w_ = 8; w_ >= 1; w_ >>= 1)                                        \
        _Pragma("unroll")                                                      \
        for (int r_ = 0; r_ < w_; ++r_) red[r_] = fmaxf(red[r_], red[r_+w_]);  \
    float pm = cross32_max(red[0]);                                            \
    if (!__all(pm - m <= 8.0f)) {                                              \
        float mn = fmaxf(m, pm);                                               \
        float sc = __builtin_amdgcn_exp2f(m - mn);                             \
        m = mn; l *= sc;                                                       \
        _Pragma("unroll")                                                      \
        for (int r_ = 0; r_ < 16; ++r_) { o[0][r_] *= sc; o[1][r_] *= sc; }    \
    }                                                                          \
    _Pragma("unroll")                                                          \
    for (int r_ = 0; r_ < 16; ++r_) {                                          \
        st0[r_] = __builtin_amdgcn_exp2f(st0[r_] - m);                         \
        st1[r_] = __builtin_amdgcn_exp2f(st1[r_] - m);                         \
    }                                                                          \
    _Pragma("unroll")                                                          \
    for (int r_ = 0; r_ < 16; ++r_) red[r_] = st0[r_] + st1[r_];               \
    _Pragma("unroll")                                                          \
    for (int w_ = 8; w_ >= 1; w_ >>= 1)                                        \
        _Pragma("unroll")                                                      \
        for (int r_ = 0; r_ < w_; ++r_) red[r_] += red[r_+w_];                 \
    l += red[0];                                                               \
    f16x8 pf[4];                                                               \
    {                                                                          \
        unsigned a0 = pkf16(st0[0],  st0[1]),  a1 = pkf16(st0[2],  st0[3]);    \
        unsigned b0 = pkf16(st0[4],  st0[5]),  b1 = pkf16(st0[6],  st0[7]);    \
        unsigned c0 = pkf16(st0[8],  st0[9]),  c1 = pkf16(st0[10], st0[11]);   \
        unsigned d0 = pkf16(st0[12], st0[13]), d1 = pkf16(st0[14], st0[15]);   \
        asm("v_permlane32_swap_b32 %0, %1" : "+v"(a0), "+v"(b0));              \
        asm("v_permlane32_swap_b32 %0, %1" : "+v"(a1), "+v"(b1));              \
        asm("v_permlane32_swap_b32 %0, %1" : "+v"(c0), "+v"(d0));              \
        asm("v_permlane32_swap_b32 %0, %1" : "+v"(c1), "+v"(d1));              \
        uint4 w0; w0.x = a0; w0.y = a1; w0.z = b0; w0.w = b1;                  \
        uint4 w1; w1.x = c0; w1.y = c1; w1.z = d0; w1.w = d1;                  \
        pf[0] = __builtin_bit_cast(f16x8, w0);                                 \
        pf[1] = __builtin_bit_cast(f16x8, w1);                                 \
    }                                                                          \
    {                                                                          \
        unsigned a0 = pkf16(st1[0],  st1[1]),  a1 = pkf16(st1[2],  st1[3]);    \
        unsigned b0 = pkf16(st1[4],  st1[5]),  b1 = pkf16(st1[6],  st1[7]);    \
        unsigned c0 = pkf16(st1[8],  st1[9]),  c1 = pkf16(st1[10], st1[11]);   \
        unsigned d0 = pkf16(st1[12], st1[13]), d1 = pkf16(st1[14], st1[15]);   \
        asm("v_permlane32_swap_b32 %0, %1" : "+v"(a0), "+v"(b0));              \
        asm("v_permlane32_swap_b32 %0, %1" : "+v"(a1), "+v"(b1));              \
        asm("v_permlane32_swap_b32 %0, %1" : "+v"(c0), "+v"(d0));              \
        asm("v_permlane32_swap_b32 %0, %1" : "+v"(c1), "+v"(d1));              \
        uint4 w0; w0.x = a0; w0.y = a1; w0.z = b0; w0.w = b1;                  \
        uint4 w1; w1.x = c0; w1.y = c1; w1.z = d0; w1.w = d1;                  \
        pf[2] = __builtin_bit_cast(f16x8, w0);                                 \
        pf[3] = __builtin_bit_cast(f16x8, w1);                                 \
    }                                                                          \
    __builtin_amdgcn_s_setprio(1);                                             \
    _Pragma("unroll")                                                          \
    for (int dt_ = 0; dt_ < 2; ++dt_)                                          \
        _Pragma("unroll")                                                      \
        for (int f_ = 0; f_ < 4; ++f_)                                         \
            o[dt_] = __builtin_amdgcn_mfma_f32_32x32x16_f16(                   \
                VF[dt_*4+f_], pf[f_], o[dt_], 0, 0, 0);                        \
    __builtin_amdgcn_s_setprio(0);                                             \
} while (0)

__global__ __launch_bounds__(256, 2) void attn_kernel(
    const f16* __restrict__ Qb, const f16* __restrict__ Kb,
    const f16* __restrict__ Vt, f16* __restrict__ ctx)
{
    __shared__ f16 Ol[4][32 * 64];   // 16KB: per-warp output transpose patch
    const int tid = threadIdx.x;
    const int lane = tid & 63;
    const int wid = tid >> 6;
    const int q = lane & 31;
    const int hi = lane >> 5;
    const int bh = blockIdx.x;
    const int q0 = blockIdx.y * 128 + wid * 32;
    const f16* Qp = Qb + (size_t)bh * SEQ * HDIM;
    const f16* Kp = Kb + (size_t)bh * SEQ * HDIM;
    const f16* Vp = Vt + (size_t)bh * SEQ * HDIM;

    f16x8 qf[4];
#pragma unroll
    for (int ds = 0; ds < 4; ++ds)
        qf[ds] = *reinterpret_cast<const f16x8*>(
            Qp + (size_t)(q0 + q) * HDIM + ds * 16 + hi * 8);

    f32x16 o[2] = {};
    float m = -1e30f, l = 0.f;

    f16x8 ka[8], kn[8], va[8];
    LOADK(ka, 0);
    for (int kb = 0; kb < SEQ; kb += 128) {
        LOADV(va, kb);
        LOADK(kn, kb + 64);
        STEP(ka, va);
        LOADV(va, kb + 64);
        LOADK(ka, (kb + 128) & (SEQ - 1));
        STEP(kn, va);
    }

    // ---- epilogue: normalize, transpose via swizzled LDS, coalesced store
    float lt = cross32_add(l);
    float inv = __builtin_amdgcn_rcpf(lt);
    char* base = (char*)&Ol[wid][0];
#pragma unroll
    for (int dt = 0; dt < 2; ++dt)
#pragma unroll
        for (int rp = 0; rp < 8; ++rp) {
            int r = rp * 2;
            int d = dt * 32 + (r & 3) + 8 * (r >> 2) + 4 * hi;
            unsigned w = pkf16(o[dt][r] * inv, o[dt][r + 1] * inv);
            int byte = (q * 128 + d * 2) ^ ((q & 7) << 4);
            *reinterpret_cast<unsigned*>(base + byte) = w;
        }
    __syncthreads();
    {
        int row = lane >> 1, half = lane & 1;
        const char* rb = base + row * 128;
        int b = bh >> 4, h = bh & 15;
        f16* orow = ctx + (size_t)(b * SEQ + q0 + row) * EMBED + h * HDIM;
#pragma unroll
        for (int i = 0; i < 4; ++i) {
            int c = half * 64 + i * 16;
            int4 v = *reinterpret_cast<const int4*>(rb + (c ^ ((row & 7) << 4)));
            *reinterpret_cast<int4*>((char*)orow + c) = v;
        }
    }
}

// ---------------------------------------------------------------------------
// GEMM2: out = ctx @ Wo + bo  (M=4096, N=1024, K=1024), fp32 output.
// ---------------------------------------------------------------------------
__global__ __launch_bounds__(256, 2) void gemm_out_kernel(
    const f16* __restrict__ A, const f16* __restrict__ WT,
    const float* __restrict__ bo, float* __restrict__ out)
{
    __shared__ f16 As[128 * 32];
    __shared__ f16 Bs[128 * 32];
    const int tid = threadIdx.x;
    const int lane = tid & 63;
    const int wid = tid >> 6;
    const int wr = wid >> 1, wc = wid & 1;
    const int lhi = lane >> 4, llo = lane & 15;
    const int row0 = blockIdx.x * 128;
    const int col0 = blockIdx.y * 128;

    f32x4 acc[4][4] = {};

    for (int k0 = 0; k0 < EMBED; k0 += 32) {
        __syncthreads();
#pragma unroll
        for (int i = 0; i < 2; ++i) {
            int li = i * 256 + tid;
            int ar = li >> 2;
            int ac = (li & 3) * 8;
            f16x8 v = *reinterpret_cast<const f16x8*>(
                &A[(size_t)(row0 + ar) * EMBED + k0 + ac]);
            int byte = (ac * 2) ^ ((ar & 3) << 4);
            *reinterpret_cast<f16x8*>((char*)As + ar * 64 + byte) = v;
        }
#pragma unroll
        for (int i = 0; i < 2; ++i) {
            int li = i * 256 + tid;
            int br = li >> 2;
            int bc = (li & 3) * 8;
            f16x8 v = *reinterpret_cast<const f16x8*>(
                &WT[(size_t)(col0 + br) * EMBED + k0 + bc]);
            int byte = (bc * 2) ^ ((br & 3) << 4);
            *reinterpret_cast<f16x8*>((char*)Bs + br * 64 + byte) = v;
        }
        __syncthreads();
        f16x8 af[4], bf[4];
#pragma unroll
        for (int m = 0; m < 4; ++m) {
            int ar = wr * 64 + m * 16 + llo;
            int byte = (lhi * 16) ^ ((ar & 3) << 4);
            af[m] = *reinterpret_cast<const f16x8*>((const char*)As + ar * 64 + byte);
        }
#pragma unroll
        for (int n = 0; n < 4; ++n) {
            int br = wc * 64 + n * 16 + llo;
            int byte = (lhi * 16) ^ ((br & 3) << 4);
            bf[n] = *reinterpret_cast<const f16x8*>((const char*)Bs + br * 64 + byte);
        }
#pragma unroll
        for (int m = 0; m < 4; ++m)
#pragma unroll
            for (int n = 0; n < 4; ++n)
                acc[m][n] = __builtin_amdgcn_mfma_f32_16x16x32_f16(
                    af[m], bf[n], acc[m][n], 0, 0, 0);
    }

#pragma unroll
    for (int m = 0; m < 4; ++m)
#pragma unroll
        for (int n = 0; n < 4; ++n)
#pragma unroll
            for (int r = 0; r < 4; ++r) {
                int mg = row0 + wr * 64 + m * 16 + lhi * 4 + r;
                int ng = col0 + wc * 64 + n * 16 + llo;
                out[(size_t)mg * EMBED + ng] = acc[m][n][r] + bo[ng];
            }
}

// ---------------------------------------------------------------------------
extern "C" void kernel_launch(void* const* d_in, const int* in_sizes, int n_in,
                              void* d_out, int out_size, void* d_ws, size_t ws_size,
                              hipStream_t stream)
{
    const float* x     = (const float*)d_in[0];
    const float* w_qkv = (const float*)d_in[1];
    const float* b_qkv = (const float*)d_in[2];
    const float* w_o   = (const float*)d_in[3];
    const float* b_o   = (const float*)d_in[4];
    float* out = (float*)d_out;

    char* ws = (char*)d_ws;
    f16* wqkvT = (f16*)ws; ws += (size_t)NQKV * EMBED * 2;
    f16* woT   = (f16*)ws; ws += (size_t)EMBED * EMBED * 2;
    f16* Qb    = (f16*)ws; ws += (size_t)BH * SEQ * HDIM * 2;
    f16* Kb    = (f16*)ws; ws += (size_t)BH * SEQ * HDIM * 2;
    f16* Vt    = (f16*)ws; ws += (size_t)BH * SEQ * HDIM * 2;
    f16* ctx   = (f16*)ws; ws += (size_t)MTOK * EMBED * 2;

    hipLaunchKernelGGL(transpose_cvt_kernel, dim3(NQKV / 32, EMBED / 32), dim3(256),
                       0, stream, w_qkv, wqkvT, EMBED, NQKV);
    hipLaunchKernelGGL(transpose_cvt_kernel, dim3(EMBED / 32, EMBED / 32), dim3(256),
                       0, stream, w_o, woT, EMBED, EMBED);
    hipLaunchKernelGGL(gemm_qkv_kernel, dim3(MTOK / 128, NQKV / 128), dim3(256),
                       0, stream, x, wqkvT, b_qkv, Qb, Kb, Vt);
    hipLaunchKernelGGL(attn_kernel, dim3(BH, SEQ / 128), dim3(256),
                       0, stream, Qb, Kb, Vt, ctx);
    hipLaunchKernelGGL(gemm_out_kernel, dim3(MTOK / 128, EMBED / 128), dim3(256),
                       0, stream, ctx, woT, b_o, out);
}